// Round 9
// baseline (30821.997 us; speedup 1.0000x reference)
//
#include <hip/hip_runtime.h>
#include <math.h>

#define T_STEPS 512
#define BATCH   128
#define HDIM    300
#define M       20
#define M2      10   // j's owned per block

// ---------------- JAX threefry2x32 noise replication ----------------
__device__ __forceinline__ unsigned rotl32(unsigned v, int r) {
    return (v << r) | (v >> (32 - r));
}

__device__ float jax_noise(unsigned i) {
#pragma clang fp contract(off)
    unsigned x0 = 0u;
    unsigned x1 = i;
    const unsigned ks0 = 0u, ks1 = 42u, ks2 = 0u ^ 42u ^ 0x1BD11BDAu;
    x0 += ks0; x1 += ks1;
    x0 += x1; x1 = rotl32(x1, 13); x1 ^= x0;
    x0 += x1; x1 = rotl32(x1, 15); x1 ^= x0;
    x0 += x1; x1 = rotl32(x1, 26); x1 ^= x0;
    x0 += x1; x1 = rotl32(x1, 6);  x1 ^= x0;
    x0 += ks1; x1 += ks2 + 1u;
    x0 += x1; x1 = rotl32(x1, 17); x1 ^= x0;
    x0 += x1; x1 = rotl32(x1, 29); x1 ^= x0;
    x0 += x1; x1 = rotl32(x1, 16); x1 ^= x0;
    x0 += x1; x1 = rotl32(x1, 24); x1 ^= x0;
    x0 += ks2; x1 += ks0 + 2u;
    x0 += x1; x1 = rotl32(x1, 13); x1 ^= x0;
    x0 += x1; x1 = rotl32(x1, 15); x1 ^= x0;
    x0 += x1; x1 = rotl32(x1, 26); x1 ^= x0;
    x0 += x1; x1 = rotl32(x1, 6);  x1 ^= x0;
    x0 += ks0; x1 += ks1 + 3u;
    x0 += x1; x1 = rotl32(x1, 17); x1 ^= x0;
    x0 += x1; x1 = rotl32(x1, 29); x1 ^= x0;
    x0 += x1; x1 = rotl32(x1, 16); x1 ^= x0;
    x0 += x1; x1 = rotl32(x1, 24); x1 ^= x0;
    x0 += ks1; x1 += ks2 + 4u;
    x0 += x1; x1 = rotl32(x1, 13); x1 ^= x0;
    x0 += x1; x1 = rotl32(x1, 15); x1 ^= x0;
    x0 += x1; x1 = rotl32(x1, 26); x1 ^= x0;
    x0 += x1; x1 = rotl32(x1, 6);  x1 ^= x0;
    x0 += ks2; x1 += ks0 + 5u;

    const unsigned bits = x0 ^ x1;
    const unsigned fb = (bits >> 9) | 0x3f800000u;
    float f = __uint_as_float(fb) - 1.0f;
    const float span = 1.0f - 0.01f;
    float v = f * span;
    v = v + 0.01f;
    return fmaxf(0.01f, v);
}

#define FOR5(X) X(0) X(1) X(2) X(3) X(4)

// ---------------- paired persistent kernel (R9) ----------------
// grid = 256 blocks: bid -> batch b = bid&127, j-half = bid>>7 (rows jb2..jb2+9).
// Partner bid^128. Exchange 10 sim floats/step (agent-scope release/acquire).
//
// Phase B (R9): K-sliced, WAVE-ALIGNED (no intra-wave divergence):
//   wave w: slice s = w&1 (k 0-151 / 152-299); idx = (w>>1)*64+lane, active<300;
//   thread: 2 cols x 5 rows x K/2, 20 named scalar accumulators.
//   Each sh_mem float4 read feeds 16 FMAs; LDS reads/CU/step ~1900 (R6: 4500).
//   Slice buffers sh_simS/candS[2]: exclusive writers, summed in finish/D.
// Phase A (R6 structure): waves 0-4 -> hb1+ent; waves 5-9 -> hwu. Separate loop
// (R8 lesson: fusing into B's loop costs more in register rotation than it hides).
// h from global L1 (R7-proven) -> 4 barriers/step. Weight-only 1-ahead prefetch.
__global__ void __launch_bounds__(640, 3)
wm_kernel(const float* __restrict__ hs,   // (T,B,H)
          const float* __restrict__ msk,  // (T,B)
          const float* __restrict__ We1,  // (300,300)
          const float* __restrict__ be1,  // (300)
          const float* __restrict__ We2,  // (300,1)
          const float* __restrict__ be2,  // (1)
          const float* __restrict__ Ws1,  // (901,300)
          const float* __restrict__ bs1,  // (300)
          const float* __restrict__ Ws2,  // (300,1)
          const float* __restrict__ bs2,  // (1)
          const float* __restrict__ Wu,   // (600,300)
          const float* __restrict__ bu,   // (300)
          float* __restrict__ out,
          float* __restrict__ ws)         // d_ws: vals[256][16] @0, flags @+16KB
{
    __shared__ __align__(16) float sh_mem[M2][HDIM];
    __shared__ __align__(16) float sh_simS[2][M2][HDIM];
    __shared__ __align__(16) float sh_candS[2][M2][HDIM];
    __shared__ __align__(16) float sh_usage[5632];   // [M] used; pad -> LDS >80KB (1 block/CU)
    __shared__ float sh_simpart[5][M2];
    __shared__ float sh_entpart[5];
    __shared__ float sh_ow[M];
    __shared__ float sh_indv[M];

    const int bid   = blockIdx.x;
    const int b     = bid & 127;
    const int jhalf = bid >> 7;
    const int jb2   = jhalf * 10;         // own global j-base
    const int pbase = 10 - jb2;           // partner global j-base
    const int pbid  = bid ^ 128;

    float*    vals_me = ws + (size_t)bid * 16;
    float*    vals_p  = ws + (size_t)pbid * 16;
    unsigned* flag_me = (unsigned*)(ws + 4096) + (size_t)bid * 16;
    unsigned* flag_p  = (unsigned*)(ws + 4096) + (size_t)pbid * 16;

    const int tid  = threadIdx.x;
    const int wave = tid >> 6;   // 0..9
    const int lane = tid & 63;

    // ---- Phase A / sim-finish / Phase D mapping (R6) ----
    const bool lower = tid < 320;
    const int cA     = lower ? tid : (tid - 320);
    const bool actA  = cA < HDIM;

    // ---- Phase B mapping: wave-aligned K-slices ----
    const int  sB   = wave & 1;               // K-slice (uniform per wave)
    const int  idxB = (wave >> 1) * 64 + lane; // 0..319
    const bool actB = idxB < 300;
    const int  g2   = idxB / 150;             // row-group 0/1 (jl = 0 or 5)
    const int  pB   = idxB % 150;             // column-pair
    const int  c0   = 2 * pB;
    const int  jl   = g2 * 5;
    const int  kbeg = sB ? 152 : 0;
    const int  kend = sB ? 300 : 152;

    // ---- init state ----
    for (int idx = tid; idx < M2 * HDIM; idx += 640) ((float*)sh_mem)[idx] = 0.0f;
    if (tid < M) sh_usage[tid] = 0.0f;

    const float be2v = be2[0];
    const float bs2v = bs2[0];
    // step-invariant per-column scalars (Phase A / finish roles)
    float bs1c = 0.f, be1c = 0.f, we2c = 0.f, ws2c = 0.f, w900c = 0.f, buc = 0.f;
    if (actA) {
        if (lower) {
            bs1c = bs1[cA]; be1c = be1[cA]; we2c = We2[cA];
            ws2c = Ws2[cA]; w900c = Ws1[900 * 300 + cA];
        } else {
            buc = bu[cA];
        }
    }
    __syncthreads();

    for (int t = 0; t < T_STEPS; ++t) {
        const int tb = t * BATCH + b;
        const float* __restrict__ hrow = hs + (size_t)tb * HDIM;   // L1-resident

        // ---- Phase A: h-GEMVs (separate loop; R8 fusion lesson) ----
        float hb1reg = 0.f, hwureg = 0.f;
        {
            float a1 = 0.f, ae = 0.f, au = 0.f;
            if (actA) {
                if (lower) {
                    const float* pB_ = Ws1 + 90000 + cA;  // rows 300..599
                    const float* pE  = We1 + cA;
                    for (int k = 0; k < HDIM; k += 4) {
                        float4 h4 = *(const float4*)&hrow[k];
                        const float* q  = pB_ + k * 300;
                        const float* qe = pE + k * 300;
                        a1 += h4.x * q[0]  + h4.y * q[300]  + h4.z * q[600]  + h4.w * q[900];
                        ae += h4.x * qe[0] + h4.y * qe[300] + h4.z * qe[600] + h4.w * qe[900];
                    }
                } else {
                    const float* pU = Wu + cA;            // rows 0..299
                    for (int k = 0; k < HDIM; k += 4) {
                        float4 h4 = *(const float4*)&hrow[k];
                        const float* q = pU + k * 300;
                        au += h4.x * q[0] + h4.y * q[300] + h4.z * q[600] + h4.w * q[900];
                    }
                }
            }
            if (lower) {
                float er = actA ? (fmaxf(ae + be1c, 0.0f) * we2c) : 0.0f;
                for (int off = 32; off; off >>= 1) er += __shfl_xor(er, off, 64);
                if (lane == 0) sh_entpart[wave] = er;
                hb1reg = a1 + bs1c;
            } else {
                hwureg = au + buc;
            }
        }

        // ---- Phase B: 2 cols x 5 rows x K-slice per thread ----
#define DECL_ACC(jj) float aS0_##jj = 0.f, aS1_##jj = 0.f, aC0_##jj = 0.f, aC1_##jj = 0.f;
        FOR5(DECL_ACC)
#undef DECL_ACC
        if (actB) {
            const float* qa = Ws1 + c0;            // rows 0..299   (mem)
            const float* qc = Ws1 + 180000 + c0;   // rows 600..899 (h*mem)
            const float* qu = Wu + 90000 + c0;     // rows 300..599 (mem)
            // preload k=kbeg weight block (12 float2)
            const float* ia = qa + kbeg * 300;
            const float* ic = qc + kbeg * 300;
            const float* iu = qu + kbeg * 300;
            float2 A0 = *(const float2*)(ia);
            float2 A1 = *(const float2*)(ia + 300);
            float2 A2 = *(const float2*)(ia + 600);
            float2 A3 = *(const float2*)(ia + 900);
            float2 C0 = *(const float2*)(ic);
            float2 C1 = *(const float2*)(ic + 300);
            float2 C2 = *(const float2*)(ic + 600);
            float2 C3 = *(const float2*)(ic + 900);
            float2 U0 = *(const float2*)(iu);
            float2 U1 = *(const float2*)(iu + 300);
            float2 U2 = *(const float2*)(iu + 600);
            float2 U3 = *(const float2*)(iu + 900);
            for (int k = kbeg; k < kend; k += 4) {
                const int kn = (k + 4 < kend) ? (k + 4) : kbeg;   // clamped prefetch
                const float* na = qa + kn * 300;
                const float* nc = qc + kn * 300;
                const float* nu = qu + kn * 300;
                float2 NA0 = *(const float2*)(na);
                float2 NA1 = *(const float2*)(na + 300);
                float2 NA2 = *(const float2*)(na + 600);
                float2 NA3 = *(const float2*)(na + 900);
                float2 NC0 = *(const float2*)(nc);
                float2 NC1 = *(const float2*)(nc + 300);
                float2 NC2 = *(const float2*)(nc + 600);
                float2 NC3 = *(const float2*)(nc + 900);
                float2 NU0 = *(const float2*)(nu);
                float2 NU1 = *(const float2*)(nu + 300);
                float2 NU2 = *(const float2*)(nu + 600);
                float2 NU3 = *(const float2*)(nu + 900);

                float4 h4 = *(const float4*)&hrow[k];
                float w00 = fmaf(h4.x, C0.x, A0.x);
                float w01 = fmaf(h4.y, C1.x, A1.x);
                float w02 = fmaf(h4.z, C2.x, A2.x);
                float w03 = fmaf(h4.w, C3.x, A3.x);
                float w10 = fmaf(h4.x, C0.y, A0.y);
                float w11 = fmaf(h4.y, C1.y, A1.y);
                float w12 = fmaf(h4.z, C2.y, A2.y);
                float w13 = fmaf(h4.w, C3.y, A3.y);
#define ACC_J(jj) { \
                float4 mv = *(const float4*)&sh_mem[jl + jj][k]; \
                aS0_##jj += mv.x * w00 + mv.y * w01 + mv.z * w02 + mv.w * w03; \
                aS1_##jj += mv.x * w10 + mv.y * w11 + mv.z * w12 + mv.w * w13; \
                aC0_##jj += mv.x * U0.x + mv.y * U1.x + mv.z * U2.x + mv.w * U3.x; \
                aC1_##jj += mv.x * U0.y + mv.y * U1.y + mv.z * U2.y + mv.w * U3.y; }
                FOR5(ACC_J)
#undef ACC_J
                A0 = NA0; A1 = NA1; A2 = NA2; A3 = NA3;
                C0 = NC0; C1 = NC1; C2 = NC2; C3 = NC3;
                U0 = NU0; U1 = NU1; U2 = NU2; U3 = NU3;
            }
#define WB(jj) { \
            *(float2*)&sh_simS[sB][jl + jj][c0]  = make_float2(aS0_##jj, aS1_##jj); \
            *(float2*)&sh_candS[sB][jl + jj][c0] = make_float2(aC0_##jj, aC1_##jj); }
            FOR5(WB)
#undef WB
        }
        __syncthreads();   // (1) sim/cand slice partials + entpart ready

        // ---- sim finish: sum slices, relu(.)*Ws2, reduce over cols (lower) ----
        if (lower) {
#pragma unroll
            for (int jj = 0; jj < M2; ++jj) {
                float v = 0.f;
                if (actA) {
                    float pre = sh_simS[0][jj][cA] + sh_simS[1][jj][cA]
                              + hb1reg + sh_usage[jb2 + jj] * w900c;
                    v = fmaxf(pre, 0.0f) * ws2c;
                }
                for (int off = 32; off; off >>= 1) v += __shfl_xor(v, off, 64);
                if (lane == 0) sh_simpart[wave][jj] = v;
            }
        }
        __syncthreads();   // (2)

        // ---- Phase C: exchange + decision (wave 0; redundant on both halves) ----
        if (wave == 0) {
            float sown = 0.f;
            if (lane < M2) {
                sown = sh_simpart[0][lane] + sh_simpart[1][lane] + sh_simpart[2][lane]
                     + sh_simpart[3][lane] + sh_simpart[4][lane];
                __hip_atomic_store(&vals_me[lane], sown, __ATOMIC_RELAXED,
                                   __HIP_MEMORY_SCOPE_AGENT);
            }
            if (lane == 0) {
                __hip_atomic_store(flag_me, (unsigned)(t + 1), __ATOMIC_RELEASE,
                                   __HIP_MEMORY_SCOPE_AGENT);
                while (__hip_atomic_load(flag_p, __ATOMIC_ACQUIRE,
                                         __HIP_MEMORY_SCOPE_AGENT) < (unsigned)(t + 1))
                    __builtin_amdgcn_s_sleep(1);
            }
            float pvv = 0.f;
            if (lane >= pbase && lane < pbase + M2)
                pvv = __hip_atomic_load(&vals_p[lane - pbase], __ATOMIC_ACQUIRE,
                                        __HIP_MEMORY_SCOPE_AGENT);
            const float myv = __shfl(sown, lane - jb2, 64);

            const bool act = lane < M;
            const bool own = act && (lane >= jb2) && (lane < jb2 + M2);
            float simj = -INFINITY, usg = 0.0f;
            if (act) {
                simj = (own ? myv : pvv) + bs2v;
                usg  = sh_usage[lane];
            }
            float es = sh_entpart[0] + sh_entpart[1] + sh_entpart[2]
                     + sh_entpart[3] + sh_entpart[4] + be2v;
            const float entp = (1.0f / (1.0f + expf(-es))) * msk[tb];

            const float coref = (act && usg > 0.0f) ? 1.0f : 0.0f;
            float comb = act ? ((usg > 0.0f) ? simj : -10000.0f) : -INFINITY;
            float mx = comb;
            for (int off = 32; off; off >>= 1) mx = fmaxf(mx, __shfl_xor(mx, off, 64));
            mx = fmaxf(mx, 0.0f);
            float e = act ? expf(comb - mx) : 0.0f;
            const float eM = expf(0.0f - mx);
            float den = e;
            for (int off = 32; off; off >>= 1) den += __shfl_xor(den, off, 64);
            den += eM;
            const float prob  = e / den;
            const float probM = eM / den;
            float masked = prob * coref;
            float msum = masked;
            for (int off = 32; off; off >>= 1) msum += __shfl_xor(msum, off, 64);
            msum += probM;
            const float dn = msum + 1e-8f;
            const float normj = masked / dn;
            const float normM = probM / dn;
            const float indv = act ? (entp * normj) : 0.0f;
            const float ow_base = entp * normM;

            // nsim = softmax(sim)
            float nmx = simj;
            for (int off = 32; off; off >>= 1) nmx = fmaxf(nmx, __shfl_xor(nmx, off, 64));
            float ne = act ? expf(simj - nmx) : 0.0f;
            float ns = ne;
            for (int off = 32; off; off >>= 1) ns += __shfl_xor(ns, off, 64);
            const float nsim = ne / ns;

            float ows = act ? (((usg == 0.0f) ? nsim * 100000.0f : 0.0f) + (1.0f - usg))
                            : -INFINITY;
            float mv = ows;
            for (int off = 32; off; off >>= 1) mv = fmaxf(mv, __shfl_xor(mv, off, 64));

            float key = 0.0f;
            if (act && ows == mv) key = jax_noise((unsigned)(tb * M + lane));
            float bv = act ? key : -1.0f;
            int bi = act ? lane : 1023;
            for (int off = 32; off; off >>= 1) {
                float ov = __shfl_xor(bv, off, 64);
                int oi = __shfl_xor(bi, off, 64);
                if (ov > bv || (ov == bv && oi < bi)) { bv = ov; bi = oi; }
            }
            const float ow = (act && lane == bi) ? ow_base : 0.0f;
            const float nu = fminf(1.0f, (ow + indv) + 0.98f * usg);

            if (act) {
                sh_ow[lane] = ow;
                sh_indv[lane] = indv;
                sh_usage[lane] = nu;
            }
            if (own) {
                const int base = tb * M + lane;
                out[65536 + base]   = nu;                                   // usage_seq
                out[1376256 + base] = indv * (1.0f - 1e-8f) + 1e-8f;        // coref
                out[2686976 + base] = ow * (1.0f - 1e-8f) + 1e-8f;          // overwrite
            }
            if (jhalf == 0 && lane == 0) out[tb] = entp * (1.0f - 1e-8f) + 1e-8f; // ent
        }
        __syncthreads();   // (3)

        // ---- Phase D: memory update (upper threads hold hwureg; own 10 rows) ----
        if (!lower && actA) {
            const float hc = hrow[cA];
#pragma unroll
            for (int jj = 0; jj < M2; ++jj) {
                const float owj = sh_ow[jb2 + jj];
                const float inj = sh_indv[jb2 + jj];
                const float cd  = tanhf(sh_candS[0][jj][cA] + sh_candS[1][jj][cA] + hwureg);
                const float mo  = sh_mem[jj][cA];
                sh_mem[jj][cA] = owj * hc + (1.0f - owj - inj) * mo + inj * cd;
            }
        }
        __syncthreads();   // (4)
    }
}

extern "C" void kernel_launch(void* const* d_in, const int* in_sizes, int n_in,
                              void* d_out, int out_size, void* d_ws, size_t ws_size,
                              hipStream_t stream) {
    (void)in_sizes; (void)n_in; (void)ws_size; (void)out_size;
    const float* hs  = (const float*)d_in[0];
    const float* msk = (const float*)d_in[1];
    const float* We1 = (const float*)d_in[2];
    const float* be1 = (const float*)d_in[3];
    const float* We2 = (const float*)d_in[4];
    const float* be2 = (const float*)d_in[5];
    const float* Ws1 = (const float*)d_in[6];
    const float* bs1 = (const float*)d_in[7];
    const float* Ws2 = (const float*)d_in[8];
    const float* bs2 = (const float*)d_in[9];
    const float* Wu  = (const float*)d_in[10];
    const float* bu  = (const float*)d_in[11];
    float* out = (float*)d_out;

    // zero the sync flags/vals (stream-ordered, graph-capturable)
    hipMemsetAsync(d_ws, 0, 64 * 1024, stream);
    hipLaunchKernelGGL(wm_kernel, dim3(256), dim3(640), 0, stream,
                       hs, msk, We1, be1, We2, be2, Ws1, bs1, Ws2, bs2, Wu, bu,
                       out, (float*)d_ws);
}

// Round 11
// 24369.308 us; speedup vs baseline: 1.2648x; 1.2648x over previous
//
#include <hip/hip_runtime.h>
#include <math.h>

#define T_STEPS 512
#define BATCH   128
#define HDIM    300
#define M       20
#define M2      10   // j's owned per block

// ---------------- JAX threefry2x32 noise replication ----------------
__device__ __forceinline__ unsigned rotl32(unsigned v, int r) {
    return (v << r) | (v >> (32 - r));
}

__device__ float jax_noise(unsigned i) {
#pragma clang fp contract(off)
    unsigned x0 = 0u;
    unsigned x1 = i;
    const unsigned ks0 = 0u, ks1 = 42u, ks2 = 0u ^ 42u ^ 0x1BD11BDAu;
    x0 += ks0; x1 += ks1;
    x0 += x1; x1 = rotl32(x1, 13); x1 ^= x0;
    x0 += x1; x1 = rotl32(x1, 15); x1 ^= x0;
    x0 += x1; x1 = rotl32(x1, 26); x1 ^= x0;
    x0 += x1; x1 = rotl32(x1, 6);  x1 ^= x0;
    x0 += ks1; x1 += ks2 + 1u;
    x0 += x1; x1 = rotl32(x1, 17); x1 ^= x0;
    x0 += x1; x1 = rotl32(x1, 29); x1 ^= x0;
    x0 += x1; x1 = rotl32(x1, 16); x1 ^= x0;
    x0 += x1; x1 = rotl32(x1, 24); x1 ^= x0;
    x0 += ks2; x1 += ks0 + 2u;
    x0 += x1; x1 = rotl32(x1, 13); x1 ^= x0;
    x0 += x1; x1 = rotl32(x1, 15); x1 ^= x0;
    x0 += x1; x1 = rotl32(x1, 26); x1 ^= x0;
    x0 += x1; x1 = rotl32(x1, 6);  x1 ^= x0;
    x0 += ks0; x1 += ks1 + 3u;
    x0 += x1; x1 = rotl32(x1, 17); x1 ^= x0;
    x0 += x1; x1 = rotl32(x1, 29); x1 ^= x0;
    x0 += x1; x1 = rotl32(x1, 16); x1 ^= x0;
    x0 += x1; x1 = rotl32(x1, 24); x1 ^= x0;
    x0 += ks1; x1 += ks2 + 4u;
    x0 += x1; x1 = rotl32(x1, 13); x1 ^= x0;
    x0 += x1; x1 = rotl32(x1, 15); x1 ^= x0;
    x0 += x1; x1 = rotl32(x1, 26); x1 ^= x0;
    x0 += x1; x1 = rotl32(x1, 6);  x1 ^= x0;
    x0 += ks2; x1 += ks0 + 5u;

    const unsigned bits = x0 ^ x1;
    const unsigned fb = (bits >> 9) | 0x3f800000u;
    float f = __uint_as_float(fb) - 1.0f;
    const float span = 1.0f - 0.01f;
    float v = f * span;
    v = v + 0.01f;
    return fmaxf(0.01f, v);
}

#define FOR5(X) X(0) X(1) X(2) X(3) X(4)

// ---------------- paired persistent kernel (R11 = R10 resubmit) ----------------
// grid = 256 blocks: bid -> batch b = bid&127, j-half = bid>>7 (rows jb2..jb2+9).
// Partner bid^128 (same XCD under %8 round-robin). Exchange 10 sim floats/step.
//
// R10/R11 = R6 structure (the 23.2ms best: LDS h, all-wave B, 1 col x 5 rows x
// full K, separate Phase A) with three verified-safe changes:
//  1. COL-ALIGNED mapping: g0 = tid 0-299 (c=tid, rows 0-4), g1 = tid 320-619
//     (c=tid-320, rows 5-9) so Phase-B accumulators line up with Phase-A
//     columns -> sim/cand staging LDS ELIMINATED; sim-finish and Phase D
//     consume the 10 per-thread accumulator registers directly.
//  2. Phase A gets the same 1-ahead rotation prefetch as B (in-loop global
//     loads drain vmcnt otherwise -- the R7/R8/R9 regression mechanism:
//     vmcnt is in-order, so a same-iteration global load forces a full
//     prefetch-queue drain. h therefore stays in LDS).
//  3. 4 barriers/step (end-of-step barrier dropped: D consumes h from a
//     register saved before Phase C; hazard audit in comments at Phase D).
__global__ void __launch_bounds__(640, 3)
wm_kernel(const float* __restrict__ hs,   // (T,B,H)
          const float* __restrict__ msk,  // (T,B)
          const float* __restrict__ We1,  // (300,300)
          const float* __restrict__ be1,  // (300)
          const float* __restrict__ We2,  // (300,1)
          const float* __restrict__ be2,  // (1)
          const float* __restrict__ Ws1,  // (901,300)
          const float* __restrict__ bs1,  // (300)
          const float* __restrict__ Ws2,  // (300,1)
          const float* __restrict__ bs2,  // (1)
          const float* __restrict__ Wu,   // (600,300)
          const float* __restrict__ bu,   // (300)
          float* __restrict__ out,
          float* __restrict__ ws)         // d_ws: vals[256][16] @0, flags @+16KB
{
    __shared__ __align__(16) float sh_mem[M2][HDIM];
    __shared__ __align__(16) float sh_h[HDIM];
    __shared__ __align__(16) float sh_hb1[HDIM];
    __shared__ __align__(16) float sh_hwu[HDIM];
    __shared__ __align__(16) float sh_usage[16384]; // [M] used; pad -> LDS >80KB (1 block/CU)
    __shared__ float sh_simpart[10][5];
    __shared__ float sh_entpart[5];
    __shared__ float sh_ow[M];
    __shared__ float sh_indv[M];

    const int bid   = blockIdx.x;
    const int b     = bid & 127;
    const int jhalf = bid >> 7;
    const int jb2   = jhalf * 10;         // own global j-base
    const int pbase = 10 - jb2;           // partner global j-base
    const int pbid  = bid ^ 128;

    float*    vals_me = ws + (size_t)bid * 16;
    float*    vals_p  = ws + (size_t)pbid * 16;
    unsigned* flag_me = (unsigned*)(ws + 4096) + (size_t)bid * 16;
    unsigned* flag_p  = (unsigned*)(ws + 4096) + (size_t)pbid * 16;

    const int tid  = threadIdx.x;
    const int wave = tid >> 6;   // 0..9
    const int lane = tid & 63;

    // ---- col-aligned mapping: both A and B use the SAME column c ----
    const bool lower   = tid < 320;
    const int  c       = lower ? tid : (tid - 320);
    const bool act     = c < HDIM;        // tid 300-319 and 620-639 idle
    const int  rowbase = lower ? 0 : 5;   // local mem rows owned in B/D

    // ---- init state ----
    for (int idx = tid; idx < M2 * HDIM; idx += 640) ((float*)sh_mem)[idx] = 0.0f;
    if (tid < M) sh_usage[tid] = 0.0f;

    const float be2v = be2[0];
    const float bs2v = bs2[0];
    // step-invariant per-column scalars (both halves need ws2c/w900c now)
    float bs1c = 0.f, be1c = 0.f, we2c = 0.f, ws2c = 0.f, w900c = 0.f, buc = 0.f;
    if (act) {
        ws2c  = Ws2[c];
        w900c = Ws1[900 * 300 + c];
        if (lower) {
            bs1c = bs1[c]; be1c = be1[c]; we2c = We2[c];
        } else {
            buc = bu[c];
        }
    }
    __syncthreads();

    for (int t = 0; t < T_STEPS; ++t) {
        const int tb = t * BATCH + b;

        // ---- load h (upper half writes; D below reads h from a REGISTER,
        //      so this write cannot race with the previous step's D) ----
        if (!lower && act) sh_h[c] = hs[(size_t)tb * HDIM + c];
        __syncthreads();   // (1) h ready; prev-step D (sh_mem writes) done

        // ---- Phase A: h-GEMVs with 1-ahead prefetch (vmcnt discipline) ----
        float hb1reg = 0.f, hwureg = 0.f;
        if (lower) {
            float a1 = 0.f, ae = 0.f;
            if (act) {
                const float* q  = Ws1 + 90000 + c;   // rows 300..599
                const float* qe = We1 + c;
                float Q0 = q[0], Q1 = q[300], Q2 = q[600], Q3 = q[900];
                float E0 = qe[0], E1 = qe[300], E2 = qe[600], E3 = qe[900];
                for (int k = 0; k < HDIM; k += 4) {
                    const int kn = (k + 4 < HDIM) ? (k + 4) : 0;
                    const float* nq = q + kn * 300;
                    const float* nE = qe + kn * 300;
                    float NQ0 = nq[0], NQ1 = nq[300], NQ2 = nq[600], NQ3 = nq[900];
                    float NE0 = nE[0], NE1 = nE[300], NE2 = nE[600], NE3 = nE[900];
                    float4 h4 = *(const float4*)&sh_h[k];
                    a1 += h4.x * Q0 + h4.y * Q1 + h4.z * Q2 + h4.w * Q3;
                    ae += h4.x * E0 + h4.y * E1 + h4.z * E2 + h4.w * E3;
                    Q0 = NQ0; Q1 = NQ1; Q2 = NQ2; Q3 = NQ3;
                    E0 = NE0; E1 = NE1; E2 = NE2; E3 = NE3;
                }
            }
            float er = act ? (fmaxf(ae + be1c, 0.0f) * we2c) : 0.0f;
            for (int off = 32; off; off >>= 1) er += __shfl_xor(er, off, 64);
            if (lane == 0) sh_entpart[wave] = er;
            hb1reg = a1 + bs1c;
            if (act) sh_hb1[c] = hb1reg;
        } else {
            float au = 0.f;
            if (act) {
                const float* qu = Wu + c;            // rows 0..299
                float U0 = qu[0], U1 = qu[300], U2 = qu[600], U3 = qu[900];
                for (int k = 0; k < HDIM; k += 4) {
                    const int kn = (k + 4 < HDIM) ? (k + 4) : 0;
                    const float* nu = qu + kn * 300;
                    float NU0 = nu[0], NU1 = nu[300], NU2 = nu[600], NU3 = nu[900];
                    float4 h4 = *(const float4*)&sh_h[k];
                    au += h4.x * U0 + h4.y * U1 + h4.z * U2 + h4.w * U3;
                    U0 = NU0; U1 = NU1; U2 = NU2; U3 = NU3;
                }
            }
            hwureg = au + buc;
            if (act) sh_hwu[c] = hwureg;
        }

        // ---- Phase B: 1 col x 5 local rows x full K (R6 loop, c-aligned) ----
#define DECL_ACC(jj) float aS_##jj = 0.f, aC_##jj = 0.f;
        FOR5(DECL_ACC)
#undef DECL_ACC
        if (act) {
            const float* qa = Ws1 + c;            // rows 0..299   (mem)
            const float* qc = Ws1 + 180000 + c;   // rows 600..899 (h*mem)
            const float* qu = Wu + 90000 + c;     // rows 300..599 (mem)
            float A0 = qa[0], A1v = qa[300], A2 = qa[600], A3 = qa[900];
            float C0 = qc[0], C1 = qc[300], C2 = qc[600], C3 = qc[900];
            float U0 = qu[0], U1 = qu[300], U2 = qu[600], U3 = qu[900];
            for (int k = 0; k < HDIM; k += 4) {
                const int kn = (k + 4 < HDIM) ? (k + 4) : 0;   // clamped prefetch
                const float* na = qa + kn * 300;
                const float* nc = qc + kn * 300;
                const float* nu = qu + kn * 300;
                float NA0 = na[0], NA1 = na[300], NA2 = na[600], NA3 = na[900];
                float NC0 = nc[0], NC1 = nc[300], NC2 = nc[600], NC3 = nc[900];
                float NU0 = nu[0], NU1 = nu[300], NU2 = nu[600], NU3 = nu[900];

                float4 h4 = *(const float4*)&sh_h[k];   // LDS: keeps vmcnt queue pure-prefetch
                float w0 = fmaf(h4.x, C0, A0);
                float w1 = fmaf(h4.y, C1, A1v);
                float w2 = fmaf(h4.z, C2, A2);
                float w3 = fmaf(h4.w, C3, A3);
#define ACC_J(jj) { \
                float4 mv = *(const float4*)&sh_mem[rowbase + jj][k]; \
                aS_##jj += mv.x * w0 + mv.y * w1 + mv.z * w2 + mv.w * w3; \
                aC_##jj += mv.x * U0 + mv.y * U1 + mv.z * U2 + mv.w * U3; }
                FOR5(ACC_J)
#undef ACC_J
                A0 = NA0; A1v = NA1; A2 = NA2; A3 = NA3;
                C0 = NC0; C1 = NC1; C2 = NC2; C3 = NC3;
                U0 = NU0; U1 = NU1; U2 = NU2; U3 = NU3;
            }
        }
        __syncthreads();   // (2) hb1/hwu/entpart visible; all B accs final

        // ---- save step-local registers for D (h, cross-half hb1/hwu) ----
        const float hreg  = act ? sh_h[c] : 0.f;
        const float myhb1 = lower ? hb1reg : (act ? sh_hb1[c] : 0.f);
        const float myhwu = lower ? (act ? sh_hwu[c] : 0.f) : hwureg;

        // ---- sim finish from REGISTERS (all 10 waves; waves 0-4 -> rows 0-4,
        //      waves 5-9 -> rows 5-9) ----
        {
            const int gbase = jb2 + rowbase;
#define SIMF(jj) { \
            float v = act ? (fmaxf(aS_##jj + myhb1 + sh_usage[gbase + jj] * w900c, 0.0f) * ws2c) : 0.0f; \
            for (int off = 32; off; off >>= 1) v += __shfl_xor(v, off, 64); \
            if (lane == 0) sh_simpart[wave][jj] = v; }
            FOR5(SIMF)
#undef SIMF
        }
        __syncthreads();   // (3)

        // ---- Phase C: exchange + decision (wave 0; redundant on both halves) ----
        if (wave == 0) {
            float sown = 0.f;
            if (lane < M2) {
                const int wb = (lane < 5) ? 0 : 5;    // waves holding this row
                const int rr = (lane < 5) ? lane : (lane - 5);
                sown = sh_simpart[wb][rr] + sh_simpart[wb + 1][rr] + sh_simpart[wb + 2][rr]
                     + sh_simpart[wb + 3][rr] + sh_simpart[wb + 4][rr];
                __hip_atomic_store(&vals_me[lane], sown, __ATOMIC_RELAXED,
                                   __HIP_MEMORY_SCOPE_AGENT);
            }
            if (lane == 0) {
                __hip_atomic_store(flag_me, (unsigned)(t + 1), __ATOMIC_RELEASE,
                                   __HIP_MEMORY_SCOPE_AGENT);
                while (__hip_atomic_load(flag_p, __ATOMIC_ACQUIRE,
                                         __HIP_MEMORY_SCOPE_AGENT) < (unsigned)(t + 1))
                    __builtin_amdgcn_s_sleep(1);
            }
            float pvv = 0.f;
            if (lane >= pbase && lane < pbase + M2)
                pvv = __hip_atomic_load(&vals_p[lane - pbase], __ATOMIC_ACQUIRE,
                                        __HIP_MEMORY_SCOPE_AGENT);
            const float myv = __shfl(sown, lane - jb2, 64);

            const bool actc = lane < M;
            const bool own  = actc && (lane >= jb2) && (lane < jb2 + M2);
            float simj = -INFINITY, usg = 0.0f;
            if (actc) {
                simj = (own ? myv : pvv) + bs2v;
                usg  = sh_usage[lane];
            }
            float es = sh_entpart[0] + sh_entpart[1] + sh_entpart[2]
                     + sh_entpart[3] + sh_entpart[4] + be2v;
            const float entp = (1.0f / (1.0f + expf(-es))) * msk[tb];

            const float coref = (actc && usg > 0.0f) ? 1.0f : 0.0f;
            float comb = actc ? ((usg > 0.0f) ? simj : -10000.0f) : -INFINITY;
            float mx = comb;
            for (int off = 32; off; off >>= 1) mx = fmaxf(mx, __shfl_xor(mx, off, 64));
            mx = fmaxf(mx, 0.0f);
            float e = actc ? expf(comb - mx) : 0.0f;
            const float eM = expf(0.0f - mx);
            float den = e;
            for (int off = 32; off; off >>= 1) den += __shfl_xor(den, off, 64);
            den += eM;
            const float prob  = e / den;
            const float probM = eM / den;
            float masked = prob * coref;
            float msum = masked;
            for (int off = 32; off; off >>= 1) msum += __shfl_xor(msum, off, 64);
            msum += probM;
            const float dn = msum + 1e-8f;
            const float normj = masked / dn;
            const float normM = probM / dn;
            const float indv = actc ? (entp * normj) : 0.0f;
            const float ow_base = entp * normM;

            // nsim = softmax(sim)
            float nmx = simj;
            for (int off = 32; off; off >>= 1) nmx = fmaxf(nmx, __shfl_xor(nmx, off, 64));
            float ne = actc ? expf(simj - nmx) : 0.0f;
            float ns = ne;
            for (int off = 32; off; off >>= 1) ns += __shfl_xor(ns, off, 64);
            const float nsim = ne / ns;

            float ows = actc ? (((usg == 0.0f) ? nsim * 100000.0f : 0.0f) + (1.0f - usg))
                             : -INFINITY;
            float mv = ows;
            for (int off = 32; off; off >>= 1) mv = fmaxf(mv, __shfl_xor(mv, off, 64));

            float key = 0.0f;
            if (actc && ows == mv) key = jax_noise((unsigned)(tb * M + lane));
            float bv = actc ? key : -1.0f;
            int bi = actc ? lane : 1023;
            for (int off = 32; off; off >>= 1) {
                float ov = __shfl_xor(bv, off, 64);
                int oi = __shfl_xor(bi, off, 64);
                if (ov > bv || (ov == bv && oi < bi)) { bv = ov; bi = oi; }
            }
            const float ow = (actc && lane == bi) ? ow_base : 0.0f;
            const float nu = fminf(1.0f, (ow + indv) + 0.98f * usg);

            if (actc) {
                sh_ow[lane] = ow;
                sh_indv[lane] = indv;
                sh_usage[lane] = nu;
            }
            if (own) {
                const int base = tb * M + lane;
                out[65536 + base]   = nu;                                   // usage_seq
                out[1376256 + base] = indv * (1.0f - 1e-8f) + 1e-8f;        // coref
                out[2686976 + base] = ow * (1.0f - 1e-8f) + 1e-8f;          // overwrite
            }
            if (jhalf == 0 && lane == 0) out[tb] = entp * (1.0f - 1e-8f) + 1e-8f; // ent
        }
        __syncthreads();   // (4)

        // ---- Phase D from REGISTERS (all act threads; own 5 rows x 1 col) ----
        // Hazard audit for dropping the end barrier: D reads sh_ow/sh_indv
        // (written in C, separated by barrier (4)), sh_mem (own cell), and
        // REGISTER hreg/aC/myhwu. Next iteration's sh_h write touches a
        // different array; next B reads sh_mem only after barrier (1).
        if (act) {
            const int gbase = jb2 + rowbase;
#define DUPD(jj) { \
            const float owj = sh_ow[gbase + jj]; \
            const float inj = sh_indv[gbase + jj]; \
            const float cd  = tanhf(aC_##jj + myhwu); \
            const float mo  = sh_mem[rowbase + jj][c]; \
            sh_mem[rowbase + jj][c] = owj * hreg + (1.0f - owj - inj) * mo + inj * cd; }
            FOR5(DUPD)
#undef DUPD
        }
    }
}

extern "C" void kernel_launch(void* const* d_in, const int* in_sizes, int n_in,
                              void* d_out, int out_size, void* d_ws, size_t ws_size,
                              hipStream_t stream) {
    (void)in_sizes; (void)n_in; (void)ws_size; (void)out_size;
    const float* hs  = (const float*)d_in[0];
    const float* msk = (const float*)d_in[1];
    const float* We1 = (const float*)d_in[2];
    const float* be1 = (const float*)d_in[3];
    const float* We2 = (const float*)d_in[4];
    const float* be2 = (const float*)d_in[5];
    const float* Ws1 = (const float*)d_in[6];
    const float* bs1 = (const float*)d_in[7];
    const float* Ws2 = (const float*)d_in[8];
    const float* bs2 = (const float*)d_in[9];
    const float* Wu  = (const float*)d_in[10];
    const float* bu  = (const float*)d_in[11];
    float* out = (float*)d_out;

    // zero the sync flags/vals (stream-ordered, graph-capturable)
    hipMemsetAsync(d_ws, 0, 64 * 1024, stream);
    hipLaunchKernelGGL(wm_kernel, dim3(256), dim3(640), 0, stream,
                       hs, msk, We1, be1, We2, be2, Ws1, bs1, Ws2, bs2, Wu, bu,
                       out, (float*)d_ws);
}

// Round 12
// 17820.848 us; speedup vs baseline: 1.7295x; 1.3675x over previous
//
#include <hip/hip_runtime.h>
#include <math.h>

#define T_STEPS 512
#define BATCH   128
#define HDIM    300
#define M       20
#define M2      10   // j's owned per block

// workspace float offsets
#define WS_SYNC_FLOATS 16384                       // 64KB sync region (vals+flags)
#define HB1_OFF  WS_SYNC_FLOATS
#define NTB      (T_STEPS * BATCH)                 // 65536
#define HBUF_FLOATS ((size_t)NTB * HDIM)           // 19,660,800
#define HWU_OFF  (HB1_OFF + HBUF_FLOATS)
#define ENT_OFF  (HWU_OFF + HBUF_FLOATS)
#define WS_NEED_BYTES ((size_t)(ENT_OFF + NTB) * 4)

// ---------------- JAX threefry2x32 noise replication ----------------
__device__ __forceinline__ unsigned rotl32(unsigned v, int r) {
    return (v << r) | (v >> (32 - r));
}

__device__ float jax_noise(unsigned i) {
#pragma clang fp contract(off)
    unsigned x0 = 0u;
    unsigned x1 = i;
    const unsigned ks0 = 0u, ks1 = 42u, ks2 = 0u ^ 42u ^ 0x1BD11BDAu;
    x0 += ks0; x1 += ks1;
    x0 += x1; x1 = rotl32(x1, 13); x1 ^= x0;
    x0 += x1; x1 = rotl32(x1, 15); x1 ^= x0;
    x0 += x1; x1 = rotl32(x1, 26); x1 ^= x0;
    x0 += x1; x1 = rotl32(x1, 6);  x1 ^= x0;
    x0 += ks1; x1 += ks2 + 1u;
    x0 += x1; x1 = rotl32(x1, 17); x1 ^= x0;
    x0 += x1; x1 = rotl32(x1, 29); x1 ^= x0;
    x0 += x1; x1 = rotl32(x1, 16); x1 ^= x0;
    x0 += x1; x1 = rotl32(x1, 24); x1 ^= x0;
    x0 += ks2; x1 += ks0 + 2u;
    x0 += x1; x1 = rotl32(x1, 13); x1 ^= x0;
    x0 += x1; x1 = rotl32(x1, 15); x1 ^= x0;
    x0 += x1; x1 = rotl32(x1, 26); x1 ^= x0;
    x0 += x1; x1 = rotl32(x1, 6);  x1 ^= x0;
    x0 += ks0; x1 += ks1 + 3u;
    x0 += x1; x1 = rotl32(x1, 17); x1 ^= x0;
    x0 += x1; x1 = rotl32(x1, 29); x1 ^= x0;
    x0 += x1; x1 = rotl32(x1, 16); x1 ^= x0;
    x0 += x1; x1 = rotl32(x1, 24); x1 ^= x0;
    x0 += ks1; x1 += ks2 + 4u;
    x0 += x1; x1 = rotl32(x1, 13); x1 ^= x0;
    x0 += x1; x1 = rotl32(x1, 15); x1 ^= x0;
    x0 += x1; x1 = rotl32(x1, 26); x1 ^= x0;
    x0 += x1; x1 = rotl32(x1, 6);  x1 ^= x0;
    x0 += ks2; x1 += ks0 + 5u;

    const unsigned bits = x0 ^ x1;
    const unsigned fb = (bits >> 9) | 0x3f800000u;
    float f = __uint_as_float(fb) - 1.0f;
    const float span = 1.0f - 0.01f;
    float v = f * span;
    v = v + 0.01f;
    return fmaxf(0.01f, v);
}

#define FOR5(X) X(0) X(1) X(2) X(3) X(4)
#define FOR8(X) X(0) X(1) X(2) X(3) X(4) X(5) X(6) X(7)

// ============ Precompute kernel: recurrence-independent h-GEMVs ============
// hb1[tb,c] = h[tb]@Ws1[300:600,c] + bs1[c]
// hwu[tb,c] = h[tb]@Wu[0:300,c]   + bu[c]
// ent[tb]   = sigmoid(relu(h@We1+be1)@We2 + be2) * msk[tb]  (also written to out)
// 8 tb-rows per block: each weight quad loaded once feeds 8 h-rows (8x L2-traffic cut).
__global__ void __launch_bounds__(320)
pre_kernel(const float* __restrict__ hs,  const float* __restrict__ msk,
           const float* __restrict__ We1, const float* __restrict__ be1,
           const float* __restrict__ We2, const float* __restrict__ be2,
           const float* __restrict__ Ws1, const float* __restrict__ bs1,
           const float* __restrict__ Wu,  const float* __restrict__ bu,
           float* __restrict__ out, float* __restrict__ ws)
{
    __shared__ __align__(16) float sh_h[8][HDIM];
    __shared__ float sh_ent[5][8];

    float* hb1buf = ws + HB1_OFF;
    float* hwubuf = ws + HWU_OFF;
    float* entbuf = ws + ENT_OFF;

    const int tb0  = blockIdx.x * 8;
    const int tid  = threadIdx.x;
    const int wave = tid >> 6;
    const int lane = tid & 63;
    const int c    = tid;
    const bool act = c < HDIM;

    for (int i = tid; i < 8 * HDIM; i += 320)
        sh_h[i / HDIM][i % HDIM] = hs[(size_t)tb0 * HDIM + i];
    __syncthreads();

    float be1c = 0.f, we2c = 0.f, bs1c = 0.f, buc = 0.f;
    if (act) { be1c = be1[c]; we2c = We2[c]; bs1c = bs1[c]; buc = bu[c]; }

#define DECL(r) float a1_##r = 0.f, ae_##r = 0.f, au_##r = 0.f;
    FOR8(DECL)
#undef DECL
    if (act) {
        const float* q1 = Ws1 + 90000 + c;   // rows 300..599
        const float* qe = We1 + c;
        const float* qu = Wu + c;            // rows 0..299
        for (int k = 0; k < HDIM; k += 4) {
            const float* r1 = q1 + k * 300;
            const float* re = qe + k * 300;
            const float* ru = qu + k * 300;
            float w10 = r1[0], w11 = r1[300], w12 = r1[600], w13 = r1[900];
            float e0  = re[0], e1  = re[300], e2  = re[600], e3  = re[900];
            float u0  = ru[0], u1  = ru[300], u2  = ru[600], u3  = ru[900];
#define ACC(r) { float4 h4 = *(const float4*)&sh_h[r][k]; \
            a1_##r += h4.x * w10 + h4.y * w11 + h4.z * w12 + h4.w * w13; \
            ae_##r += h4.x * e0  + h4.y * e1  + h4.z * e2  + h4.w * e3;  \
            au_##r += h4.x * u0  + h4.y * u1  + h4.z * u2  + h4.w * u3; }
            FOR8(ACC)
#undef ACC
        }
#define WR(r) { hb1buf[(size_t)(tb0 + r) * HDIM + c] = a1_##r + bs1c; \
                hwubuf[(size_t)(tb0 + r) * HDIM + c] = au_##r + buc; }
        FOR8(WR)
#undef WR
    }
#define ENT(r) { float er = act ? (fmaxf(ae_##r + be1c, 0.f) * we2c) : 0.f; \
    for (int off = 32; off; off >>= 1) er += __shfl_xor(er, off, 64); \
    if (lane == 0) sh_ent[wave][r] = er; }
    FOR8(ENT)
#undef ENT
    __syncthreads();
    if (tid < 8) {
        float es = sh_ent[0][tid] + sh_ent[1][tid] + sh_ent[2][tid]
                 + sh_ent[3][tid] + sh_ent[4][tid] + be2[0];
        float entp = (1.0f / (1.0f + expf(-es))) * msk[tb0 + tid];
        entbuf[tb0 + tid] = entp;
        out[tb0 + tid] = entp * (1.0f - 1e-8f) + 1e-8f;   // ent output
    }
}

// ============ Fast recurrent kernel (Phase A removed) ============
// grid = 256 blocks: bid -> batch b = bid&127, j-half = bid>>7 (rows jb2..jb2+9).
// Per step: h->LDS, bar(1); load hb1v/hwuv (precomputed); Phase B (R11 loop);
// sim-finish from registers; bar(2); Phase C (ent precomputed); bar(3); Phase D.
__global__ void __launch_bounds__(640, 3)
wm_fast(const float* __restrict__ hs,
        const float* __restrict__ We2,   // unused, kept for symmetry
        const float* __restrict__ Ws1,
        const float* __restrict__ Ws2,
        const float* __restrict__ bs2,
        const float* __restrict__ Wu,
        float* __restrict__ out,
        float* __restrict__ ws)
{
    __shared__ __align__(16) float sh_mem[M2][HDIM];
    __shared__ __align__(16) float sh_h[HDIM];
    __shared__ __align__(16) float sh_usage[17408]; // [M] used; pad -> LDS >80KB (1 block/CU)
    __shared__ float sh_simpart[10][5];
    __shared__ float sh_ow[M];
    __shared__ float sh_indv[M];

    const float* hb1buf = ws + HB1_OFF;
    const float* hwubuf = ws + HWU_OFF;
    const float* entbuf = ws + ENT_OFF;

    const int bid   = blockIdx.x;
    const int b     = bid & 127;
    const int jhalf = bid >> 7;
    const int jb2   = jhalf * 10;
    const int pbase = 10 - jb2;
    const int pbid  = bid ^ 128;

    float*    vals_me = ws + (size_t)bid * 16;
    float*    vals_p  = ws + (size_t)pbid * 16;
    unsigned* flag_me = (unsigned*)(ws + 4096) + (size_t)bid * 16;
    unsigned* flag_p  = (unsigned*)(ws + 4096) + (size_t)pbid * 16;

    const int tid  = threadIdx.x;
    const int wave = tid >> 6;
    const int lane = tid & 63;

    const bool lower   = tid < 320;
    const int  c       = lower ? tid : (tid - 320);
    const bool act     = c < HDIM;
    const int  rowbase = lower ? 0 : 5;

    for (int idx = tid; idx < M2 * HDIM; idx += 640) ((float*)sh_mem)[idx] = 0.0f;
    if (tid < M) sh_usage[tid] = 0.0f;

    const float bs2v = bs2[0];
    float ws2c = 0.f, w900c = 0.f;
    if (act) { ws2c = Ws2[c]; w900c = Ws1[900 * 300 + c]; }
    __syncthreads();

    for (int t = 0; t < T_STEPS; ++t) {
        const int tb = t * BATCH + b;

        if (!lower && act) sh_h[c] = hs[(size_t)tb * HDIM + c];
        __syncthreads();   // (1) h ready; prev-step D/C writes done

        // precomputed per-column GEMV results (complete during B)
        const float hb1v = act ? hb1buf[(size_t)tb * HDIM + c] : 0.f;
        const float hwuv = act ? hwubuf[(size_t)tb * HDIM + c] : 0.f;
        const float hreg = act ? sh_h[c] : 0.f;

        // ---- Phase B: 1 col x 5 local rows x full K (R11-proven loop) ----
#define DECL_ACC(jj) float aS_##jj = 0.f, aC_##jj = 0.f;
        FOR5(DECL_ACC)
#undef DECL_ACC
        if (act) {
            const float* qa = Ws1 + c;            // rows 0..299   (mem)
            const float* qc = Ws1 + 180000 + c;   // rows 600..899 (h*mem)
            const float* qu = Wu + 90000 + c;     // rows 300..599 (mem)
            float A0 = qa[0], A1v = qa[300], A2 = qa[600], A3 = qa[900];
            float C0 = qc[0], C1 = qc[300], C2 = qc[600], C3 = qc[900];
            float U0 = qu[0], U1 = qu[300], U2 = qu[600], U3 = qu[900];
            for (int k = 0; k < HDIM; k += 4) {
                const int kn = (k + 4 < HDIM) ? (k + 4) : 0;   // clamped prefetch
                const float* na = qa + kn * 300;
                const float* nc = qc + kn * 300;
                const float* nu = qu + kn * 300;
                float NA0 = na[0], NA1 = na[300], NA2 = na[600], NA3 = na[900];
                float NC0 = nc[0], NC1 = nc[300], NC2 = nc[600], NC3 = nc[900];
                float NU0 = nu[0], NU1 = nu[300], NU2 = nu[600], NU3 = nu[900];

                float4 h4 = *(const float4*)&sh_h[k];
                float w0 = fmaf(h4.x, C0, A0);
                float w1 = fmaf(h4.y, C1, A1v);
                float w2 = fmaf(h4.z, C2, A2);
                float w3 = fmaf(h4.w, C3, A3);
#define ACC_J(jj) { \
                float4 mv = *(const float4*)&sh_mem[rowbase + jj][k]; \
                aS_##jj += mv.x * w0 + mv.y * w1 + mv.z * w2 + mv.w * w3; \
                aC_##jj += mv.x * U0 + mv.y * U1 + mv.z * U2 + mv.w * U3; }
                FOR5(ACC_J)
#undef ACC_J
                A0 = NA0; A1v = NA1; A2 = NA2; A3 = NA3;
                C0 = NC0; C1 = NC1; C2 = NC2; C3 = NC3;
                U0 = NU0; U1 = NU1; U2 = NU2; U3 = NU3;
            }
        }

        // ---- sim finish from registers (all 10 waves) ----
        {
            const int gbase = jb2 + rowbase;
#define SIMF(jj) { \
            float v = act ? (fmaxf(aS_##jj + hb1v + sh_usage[gbase + jj] * w900c, 0.0f) * ws2c) : 0.0f; \
            for (int off = 32; off; off >>= 1) v += __shfl_xor(v, off, 64); \
            if (lane == 0) sh_simpart[wave][jj] = v; }
            FOR5(SIMF)
#undef SIMF
        }
        __syncthreads();   // (2)

        // ---- Phase C: exchange + decision (wave 0) ----
        if (wave == 0) {
            float sown = 0.f;
            if (lane < M2) {
                const int wb = (lane < 5) ? 0 : 5;
                const int rr = (lane < 5) ? lane : (lane - 5);
                sown = sh_simpart[wb][rr] + sh_simpart[wb + 1][rr] + sh_simpart[wb + 2][rr]
                     + sh_simpart[wb + 3][rr] + sh_simpart[wb + 4][rr];
                __hip_atomic_store(&vals_me[lane], sown, __ATOMIC_RELAXED,
                                   __HIP_MEMORY_SCOPE_AGENT);
            }
            if (lane == 0) {
                __hip_atomic_store(flag_me, (unsigned)(t + 1), __ATOMIC_RELEASE,
                                   __HIP_MEMORY_SCOPE_AGENT);
                while (__hip_atomic_load(flag_p, __ATOMIC_ACQUIRE,
                                         __HIP_MEMORY_SCOPE_AGENT) < (unsigned)(t + 1))
                    __builtin_amdgcn_s_sleep(1);
            }
            float pvv = 0.f;
            if (lane >= pbase && lane < pbase + M2)
                pvv = __hip_atomic_load(&vals_p[lane - pbase], __ATOMIC_ACQUIRE,
                                        __HIP_MEMORY_SCOPE_AGENT);
            const float myv = __shfl(sown, lane - jb2, 64);

            const bool actc = lane < M;
            const bool own  = actc && (lane >= jb2) && (lane < jb2 + M2);
            float simj = -INFINITY, usg = 0.0f;
            if (actc) {
                simj = (own ? myv : pvv) + bs2v;
                usg  = sh_usage[lane];
            }
            const float entp = entbuf[tb];   // precomputed sigmoid*mask

            const float coref = (actc && usg > 0.0f) ? 1.0f : 0.0f;
            float comb = actc ? ((usg > 0.0f) ? simj : -10000.0f) : -INFINITY;
            float mx = comb;
            for (int off = 32; off; off >>= 1) mx = fmaxf(mx, __shfl_xor(mx, off, 64));
            mx = fmaxf(mx, 0.0f);
            float e = actc ? expf(comb - mx) : 0.0f;
            const float eM = expf(0.0f - mx);
            float den = e;
            for (int off = 32; off; off >>= 1) den += __shfl_xor(den, off, 64);
            den += eM;
            const float prob  = e / den;
            const float probM = eM / den;
            float masked = prob * coref;
            float msum = masked;
            for (int off = 32; off; off >>= 1) msum += __shfl_xor(msum, off, 64);
            msum += probM;
            const float dn = msum + 1e-8f;
            const float normj = masked / dn;
            const float normM = probM / dn;
            const float indv = actc ? (entp * normj) : 0.0f;
            const float ow_base = entp * normM;

            float nmx = simj;
            for (int off = 32; off; off >>= 1) nmx = fmaxf(nmx, __shfl_xor(nmx, off, 64));
            float ne = actc ? expf(simj - nmx) : 0.0f;
            float ns = ne;
            for (int off = 32; off; off >>= 1) ns += __shfl_xor(ns, off, 64);
            const float nsim = ne / ns;

            float ows = actc ? (((usg == 0.0f) ? nsim * 100000.0f : 0.0f) + (1.0f - usg))
                             : -INFINITY;
            float mv = ows;
            for (int off = 32; off; off >>= 1) mv = fmaxf(mv, __shfl_xor(mv, off, 64));

            float key = 0.0f;
            if (actc && ows == mv) key = jax_noise((unsigned)(tb * M + lane));
            float bv = actc ? key : -1.0f;
            int bi = actc ? lane : 1023;
            for (int off = 32; off; off >>= 1) {
                float ov = __shfl_xor(bv, off, 64);
                int oi = __shfl_xor(bi, off, 64);
                if (ov > bv || (ov == bv && oi < bi)) { bv = ov; bi = oi; }
            }
            const float ow = (actc && lane == bi) ? ow_base : 0.0f;
            const float nu = fminf(1.0f, (ow + indv) + 0.98f * usg);

            if (actc) {
                sh_ow[lane] = ow;
                sh_indv[lane] = indv;
                sh_usage[lane] = nu;
            }
            if (own) {
                const int base = tb * M + lane;
                out[65536 + base]   = nu;                                   // usage_seq
                out[1376256 + base] = indv * (1.0f - 1e-8f) + 1e-8f;        // coref
                out[2686976 + base] = ow * (1.0f - 1e-8f) + 1e-8f;          // overwrite
            }
            // ent output written by pre_kernel
        }
        __syncthreads();   // (3)

        // ---- Phase D from registers (own 5 rows x 1 col) ----
        if (act) {
            const int gbase = jb2 + rowbase;
#define DUPD(jj) { \
            const float owj = sh_ow[gbase + jj]; \
            const float inj = sh_indv[gbase + jj]; \
            const float cd  = tanhf(aC_##jj + hwuv); \
            const float mo  = sh_mem[rowbase + jj][c]; \
            sh_mem[rowbase + jj][c] = owj * hreg + (1.0f - owj - inj) * mo + inj * cd; }
            FOR5(DUPD)
#undef DUPD
        }
        // no end barrier: next-step bar(1) separates D's sh_mem writes from B reads
    }
}

// ============ Fallback: R11 kernel (used when ws_size < WS_NEED_BYTES) ============
__global__ void __launch_bounds__(640, 3)
wm_kernel(const float* __restrict__ hs, const float* __restrict__ msk,
          const float* __restrict__ We1, const float* __restrict__ be1,
          const float* __restrict__ We2, const float* __restrict__ be2,
          const float* __restrict__ Ws1, const float* __restrict__ bs1,
          const float* __restrict__ Ws2, const float* __restrict__ bs2,
          const float* __restrict__ Wu,  const float* __restrict__ bu,
          float* __restrict__ out, float* __restrict__ ws)
{
    __shared__ __align__(16) float sh_mem[M2][HDIM];
    __shared__ __align__(16) float sh_h[HDIM];
    __shared__ __align__(16) float sh_hb1[HDIM];
    __shared__ __align__(16) float sh_hwu[HDIM];
    __shared__ __align__(16) float sh_usage[16384];
    __shared__ float sh_simpart[10][5];
    __shared__ float sh_entpart[5];
    __shared__ float sh_ow[M];
    __shared__ float sh_indv[M];

    const int bid   = blockIdx.x;
    const int b     = bid & 127;
    const int jhalf = bid >> 7;
    const int jb2   = jhalf * 10;
    const int pbase = 10 - jb2;
    const int pbid  = bid ^ 128;

    float*    vals_me = ws + (size_t)bid * 16;
    float*    vals_p  = ws + (size_t)pbid * 16;
    unsigned* flag_me = (unsigned*)(ws + 4096) + (size_t)bid * 16;
    unsigned* flag_p  = (unsigned*)(ws + 4096) + (size_t)pbid * 16;

    const int tid  = threadIdx.x;
    const int wave = tid >> 6;
    const int lane = tid & 63;

    const bool lower   = tid < 320;
    const int  c       = lower ? tid : (tid - 320);
    const bool act     = c < HDIM;
    const int  rowbase = lower ? 0 : 5;

    for (int idx = tid; idx < M2 * HDIM; idx += 640) ((float*)sh_mem)[idx] = 0.0f;
    if (tid < M) sh_usage[tid] = 0.0f;

    const float be2v = be2[0];
    const float bs2v = bs2[0];
    float bs1c = 0.f, be1c = 0.f, we2c = 0.f, ws2c = 0.f, w900c = 0.f, buc = 0.f;
    if (act) {
        ws2c  = Ws2[c];
        w900c = Ws1[900 * 300 + c];
        if (lower) { bs1c = bs1[c]; be1c = be1[c]; we2c = We2[c]; }
        else       { buc = bu[c]; }
    }
    __syncthreads();

    for (int t = 0; t < T_STEPS; ++t) {
        const int tb = t * BATCH + b;

        if (!lower && act) sh_h[c] = hs[(size_t)tb * HDIM + c];
        __syncthreads();

        float hb1reg = 0.f, hwureg = 0.f;
        if (lower) {
            float a1 = 0.f, ae = 0.f;
            if (act) {
                const float* q  = Ws1 + 90000 + c;
                const float* qe = We1 + c;
                float Q0 = q[0], Q1 = q[300], Q2 = q[600], Q3 = q[900];
                float E0 = qe[0], E1 = qe[300], E2 = qe[600], E3 = qe[900];
                for (int k = 0; k < HDIM; k += 4) {
                    const int kn = (k + 4 < HDIM) ? (k + 4) : 0;
                    const float* nq = q + kn * 300;
                    const float* nE = qe + kn * 300;
                    float NQ0 = nq[0], NQ1 = nq[300], NQ2 = nq[600], NQ3 = nq[900];
                    float NE0 = nE[0], NE1 = nE[300], NE2 = nE[600], NE3 = nE[900];
                    float4 h4 = *(const float4*)&sh_h[k];
                    a1 += h4.x * Q0 + h4.y * Q1 + h4.z * Q2 + h4.w * Q3;
                    ae += h4.x * E0 + h4.y * E1 + h4.z * E2 + h4.w * E3;
                    Q0 = NQ0; Q1 = NQ1; Q2 = NQ2; Q3 = NQ3;
                    E0 = NE0; E1 = NE1; E2 = NE2; E3 = NE3;
                }
            }
            float er = act ? (fmaxf(ae + be1c, 0.0f) * we2c) : 0.0f;
            for (int off = 32; off; off >>= 1) er += __shfl_xor(er, off, 64);
            if (lane == 0) sh_entpart[wave] = er;
            hb1reg = a1 + bs1c;
            if (act) sh_hb1[c] = hb1reg;
        } else {
            float au = 0.f;
            if (act) {
                const float* qu = Wu + c;
                float U0 = qu[0], U1 = qu[300], U2 = qu[600], U3 = qu[900];
                for (int k = 0; k < HDIM; k += 4) {
                    const int kn = (k + 4 < HDIM) ? (k + 4) : 0;
                    const float* nu = qu + kn * 300;
                    float NU0 = nu[0], NU1 = nu[300], NU2 = nu[600], NU3 = nu[900];
                    float4 h4 = *(const float4*)&sh_h[k];
                    au += h4.x * U0 + h4.y * U1 + h4.z * U2 + h4.w * U3;
                    U0 = NU0; U1 = NU1; U2 = NU2; U3 = NU3;
                }
            }
            hwureg = au + buc;
            if (act) sh_hwu[c] = hwureg;
        }

#define DECL_ACC(jj) float aS_##jj = 0.f, aC_##jj = 0.f;
        FOR5(DECL_ACC)
#undef DECL_ACC
        if (act) {
            const float* qa = Ws1 + c;
            const float* qc = Ws1 + 180000 + c;
            const float* qu = Wu + 90000 + c;
            float A0 = qa[0], A1v = qa[300], A2 = qa[600], A3 = qa[900];
            float C0 = qc[0], C1 = qc[300], C2 = qc[600], C3 = qc[900];
            float U0 = qu[0], U1 = qu[300], U2 = qu[600], U3 = qu[900];
            for (int k = 0; k < HDIM; k += 4) {
                const int kn = (k + 4 < HDIM) ? (k + 4) : 0;
                const float* na = qa + kn * 300;
                const float* nc = qc + kn * 300;
                const float* nu = qu + kn * 300;
                float NA0 = na[0], NA1 = na[300], NA2 = na[600], NA3 = na[900];
                float NC0 = nc[0], NC1 = nc[300], NC2 = nc[600], NC3 = nc[900];
                float NU0 = nu[0], NU1 = nu[300], NU2 = nu[600], NU3 = nu[900];
                float4 h4 = *(const float4*)&sh_h[k];
                float w0 = fmaf(h4.x, C0, A0);
                float w1 = fmaf(h4.y, C1, A1v);
                float w2 = fmaf(h4.z, C2, A2);
                float w3 = fmaf(h4.w, C3, A3);
#define ACC_J(jj) { \
                float4 mv = *(const float4*)&sh_mem[rowbase + jj][k]; \
                aS_##jj += mv.x * w0 + mv.y * w1 + mv.z * w2 + mv.w * w3; \
                aC_##jj += mv.x * U0 + mv.y * U1 + mv.z * U2 + mv.w * U3; }
                FOR5(ACC_J)
#undef ACC_J
                A0 = NA0; A1v = NA1; A2 = NA2; A3 = NA3;
                C0 = NC0; C1 = NC1; C2 = NC2; C3 = NC3;
                U0 = NU0; U1 = NU1; U2 = NU2; U3 = NU3;
            }
        }
        __syncthreads();

        const float hreg  = act ? sh_h[c] : 0.f;
        const float myhb1 = lower ? hb1reg : (act ? sh_hb1[c] : 0.f);
        const float myhwu = lower ? (act ? sh_hwu[c] : 0.f) : hwureg;

        {
            const int gbase = jb2 + rowbase;
#define SIMF(jj) { \
            float v = act ? (fmaxf(aS_##jj + myhb1 + sh_usage[gbase + jj] * w900c, 0.0f) * ws2c) : 0.0f; \
            for (int off = 32; off; off >>= 1) v += __shfl_xor(v, off, 64); \
            if (lane == 0) sh_simpart[wave][jj] = v; }
            FOR5(SIMF)
#undef SIMF
        }
        __syncthreads();

        if (wave == 0) {
            float sown = 0.f;
            if (lane < M2) {
                const int wb = (lane < 5) ? 0 : 5;
                const int rr = (lane < 5) ? lane : (lane - 5);
                sown = sh_simpart[wb][rr] + sh_simpart[wb + 1][rr] + sh_simpart[wb + 2][rr]
                     + sh_simpart[wb + 3][rr] + sh_simpart[wb + 4][rr];
                __hip_atomic_store(&vals_me[lane], sown, __ATOMIC_RELAXED,
                                   __HIP_MEMORY_SCOPE_AGENT);
            }
            if (lane == 0) {
                __hip_atomic_store(flag_me, (unsigned)(t + 1), __ATOMIC_RELEASE,
                                   __HIP_MEMORY_SCOPE_AGENT);
                while (__hip_atomic_load(flag_p, __ATOMIC_ACQUIRE,
                                         __HIP_MEMORY_SCOPE_AGENT) < (unsigned)(t + 1))
                    __builtin_amdgcn_s_sleep(1);
            }
            float pvv = 0.f;
            if (lane >= pbase && lane < pbase + M2)
                pvv = __hip_atomic_load(&vals_p[lane - pbase], __ATOMIC_ACQUIRE,
                                        __HIP_MEMORY_SCOPE_AGENT);
            const float myv = __shfl(sown, lane - jb2, 64);

            const bool actc = lane < M;
            const bool own  = actc && (lane >= jb2) && (lane < jb2 + M2);
            float simj = -INFINITY, usg = 0.0f;
            if (actc) {
                simj = (own ? myv : pvv) + bs2v;
                usg  = sh_usage[lane];
            }
            float es = sh_entpart[0] + sh_entpart[1] + sh_entpart[2]
                     + sh_entpart[3] + sh_entpart[4] + be2v;
            const float entp = (1.0f / (1.0f + expf(-es))) * msk[tb];

            const float coref = (actc && usg > 0.0f) ? 1.0f : 0.0f;
            float comb = actc ? ((usg > 0.0f) ? simj : -10000.0f) : -INFINITY;
            float mx = comb;
            for (int off = 32; off; off >>= 1) mx = fmaxf(mx, __shfl_xor(mx, off, 64));
            mx = fmaxf(mx, 0.0f);
            float e = actc ? expf(comb - mx) : 0.0f;
            const float eM = expf(0.0f - mx);
            float den = e;
            for (int off = 32; off; off >>= 1) den += __shfl_xor(den, off, 64);
            den += eM;
            const float prob  = e / den;
            const float probM = eM / den;
            float masked = prob * coref;
            float msum = masked;
            for (int off = 32; off; off >>= 1) msum += __shfl_xor(msum, off, 64);
            msum += probM;
            const float dn = msum + 1e-8f;
            const float normj = masked / dn;
            const float normM = probM / dn;
            const float indv = actc ? (entp * normj) : 0.0f;
            const float ow_base = entp * normM;

            float nmx = simj;
            for (int off = 32; off; off >>= 1) nmx = fmaxf(nmx, __shfl_xor(nmx, off, 64));
            float ne = actc ? expf(simj - nmx) : 0.0f;
            float ns = ne;
            for (int off = 32; off; off >>= 1) ns += __shfl_xor(ns, off, 64);
            const float nsim = ne / ns;

            float ows = actc ? (((usg == 0.0f) ? nsim * 100000.0f : 0.0f) + (1.0f - usg))
                             : -INFINITY;
            float mv = ows;
            for (int off = 32; off; off >>= 1) mv = fmaxf(mv, __shfl_xor(mv, off, 64));

            float key = 0.0f;
            if (actc && ows == mv) key = jax_noise((unsigned)(tb * M + lane));
            float bv = actc ? key : -1.0f;
            int bi = actc ? lane : 1023;
            for (int off = 32; off; off >>= 1) {
                float ov = __shfl_xor(bv, off, 64);
                int oi = __shfl_xor(bi, off, 64);
                if (ov > bv || (ov == bv && oi < bi)) { bv = ov; bi = oi; }
            }
            const float ow = (actc && lane == bi) ? ow_base : 0.0f;
            const float nu = fminf(1.0f, (ow + indv) + 0.98f * usg);

            if (actc) {
                sh_ow[lane] = ow;
                sh_indv[lane] = indv;
                sh_usage[lane] = nu;
            }
            if (own) {
                const int base = tb * M + lane;
                out[65536 + base]   = nu;
                out[1376256 + base] = indv * (1.0f - 1e-8f) + 1e-8f;
                out[2686976 + base] = ow * (1.0f - 1e-8f) + 1e-8f;
            }
            if (jhalf == 0 && lane == 0) out[tb] = entp * (1.0f - 1e-8f) + 1e-8f;
        }
        __syncthreads();

        if (act) {
            const int gbase = jb2 + rowbase;
#define DUPD(jj) { \
            const float owj = sh_ow[gbase + jj]; \
            const float inj = sh_indv[gbase + jj]; \
            const float cd  = tanhf(aC_##jj + myhwu); \
            const float mo  = sh_mem[rowbase + jj][c]; \
            sh_mem[rowbase + jj][c] = owj * hreg + (1.0f - owj - inj) * mo + inj * cd; }
            FOR5(DUPD)
#undef DUPD
        }
    }
}

extern "C" void kernel_launch(void* const* d_in, const int* in_sizes, int n_in,
                              void* d_out, int out_size, void* d_ws, size_t ws_size,
                              hipStream_t stream) {
    (void)in_sizes; (void)n_in; (void)out_size;
    const float* hs  = (const float*)d_in[0];
    const float* msk = (const float*)d_in[1];
    const float* We1 = (const float*)d_in[2];
    const float* be1 = (const float*)d_in[3];
    const float* We2 = (const float*)d_in[4];
    const float* be2 = (const float*)d_in[5];
    const float* Ws1 = (const float*)d_in[6];
    const float* bs1 = (const float*)d_in[7];
    const float* Ws2 = (const float*)d_in[8];
    const float* bs2 = (const float*)d_in[9];
    const float* Wu  = (const float*)d_in[10];
    const float* bu  = (const float*)d_in[11];
    float* out = (float*)d_out;

    hipMemsetAsync(d_ws, 0, 64 * 1024, stream);   // sync flags/vals
    if (ws_size >= WS_NEED_BYTES) {
        hipLaunchKernelGGL(pre_kernel, dim3(NTB / 8), dim3(320), 0, stream,
                           hs, msk, We1, be1, We2, be2, Ws1, bs1, Wu, bu,
                           out, (float*)d_ws);
        hipLaunchKernelGGL(wm_fast, dim3(256), dim3(640), 0, stream,
                           hs, We2, Ws1, Ws2, bs2, Wu, out, (float*)d_ws);
    } else {
        hipLaunchKernelGGL(wm_kernel, dim3(256), dim3(640), 0, stream,
                           hs, msk, We1, be1, We2, be2, Ws1, bs1, Ws2, bs2, Wu, bu,
                           out, (float*)d_ws);
    }
}